// Round 9
// baseline (279.845 us; speedup 1.0000x reference)
//
#include <hip/hip_runtime.h>

// ---------------------------------------------------------------------------
// LongTermMemoryModule, round 9. FP32 in/out. Changes vs r8:
//  - attn_partial XCD-swizzled: h = blockIdx&7 -> all blocks on one XCD share
//    a head; K/V working set 2 MB fits the 4 MB per-XCD L2. (r6-r8 streamed
//    512 MB from Infinity Cache at ~6 TB/s == the invariant 81-83 us.)
//  - bV preloaded before the lgkmcnt fence (clobber was pinning V latency
//    into the PV critical path).
//  - convert_all deleted: consumers read fp32 and pack to bf16 in-register.
//    4 dispatches total.
// Shapes: B=32 S=64 D=512 M=8192 H=8 hd=64.
// ---------------------------------------------------------------------------

#define Dm  512
#define Mb  8192
#define BSr 2048
#define PLP 36   // P row stride (u16): 72 B rows, b64-aligned accesses

// 0.125 (1/sqrt(hd)) * log2(e): exp2 after pre-scaled QK == softmax exp
#define QSCALE 0.18033688011112042f

typedef float f32x4 __attribute__((ext_vector_type(4)));
typedef short bf16x4 __attribute__((ext_vector_type(4)));
typedef short bf16x8 __attribute__((ext_vector_type(8)));
typedef unsigned short u16x4 __attribute__((ext_vector_type(4)));
typedef unsigned short u16x8 __attribute__((ext_vector_type(8)));
typedef unsigned uint4v __attribute__((ext_vector_type(4)));

#define MFMA(a, b, c) __builtin_amdgcn_mfma_f32_16x16x32_bf16((a), (b), (c), 0, 0, 0)

#if __has_builtin(__builtin_amdgcn_exp2f)
#define EXP2F(x) __builtin_amdgcn_exp2f(x)
#else
#define EXP2F(x) __expf((x)*0.6931471805599453f)
#endif

__device__ __forceinline__ unsigned short f32_bf16(float f) {
  unsigned u = __builtin_bit_cast(unsigned, f);
  u += 0x7FFFu + ((u >> 16) & 1u);   // RNE
  return (unsigned short)(u >> 16);
}
__device__ __forceinline__ float bf16_f32(unsigned short h) {
  unsigned u = ((unsigned)h) << 16;
  return __builtin_bit_cast(float, u);
}
__device__ __forceinline__ unsigned pack_bf16_trunc(float a, float b) {
  return (__builtin_bit_cast(unsigned, a) >> 16) |
         (__builtin_bit_cast(unsigned, b) & 0xFFFF0000u);
}
// 8 consecutive fp32 -> bf16x8 fragment (truncation; 16B+16B aligned loads)
__device__ __forceinline__ bf16x8 ld8_f32_bf16(const float* __restrict__ p) {
  f32x4 a = *(const f32x4*)p;
  f32x4 b = *(const f32x4*)(p + 4);
  uint4v u;
  u[0] = pack_bf16_trunc(a[0], a[1]);
  u[1] = pack_bf16_trunc(a[2], a[3]);
  u[2] = pack_bf16_trunc(b[0], b[1]);
  u[3] = pack_bf16_trunc(b[2], b[3]);
  return __builtin_bit_cast(bf16x8, u);
}

// ---------------------------------------------------------------------------
// Fused projections, fp32 inputs read directly. Blocks [0,128): Q projection
// (q_s[bh][s][d], pre-scaled). Blocks [128,640): K+V (k_s[h][m][d],
// vT_s[h*64+d][m], LDS-staged coalesced stores).
// ---------------------------------------------------------------------------
__global__ __launch_bounds__(256) void proj_fused(
    const float* __restrict__ query,
    const float* __restrict__ bank,
    const float* __restrict__ Win,
    const float* __restrict__ bin,
    unsigned short* __restrict__ q_s,
    unsigned short* __restrict__ k_s,
    unsigned short* __restrict__ vT_s) {
  __shared__ __align__(16) unsigned short Kst[128 * 72];
  __shared__ __align__(16) unsigned short Vst[64 * 136];
  const int lane = threadIdx.x & 63;
  const int wv   = threadIdx.x >> 6;
  const int l15  = lane & 15;
  const int qd   = lane >> 4;
  const f32x4 z4 = {0.f, 0.f, 0.f, 0.f};

  if (blockIdx.x < 128) {
    // ---------------- Q projection ----------------
    const int mbase = (blockIdx.x >> 3) * 128 + wv * 32;
    const int nbase = (blockIdx.x & 7) * 64;
    f32x4 acc[2][4];
#pragma unroll
    for (int ti = 0; ti < 2; ++ti)
#pragma unroll
      for (int j = 0; j < 4; ++j) acc[ti][j] = z4;

    const float* a0p = query + (mbase + l15) * Dm + qd * 8;
    const float* a1p = a0p + 16 * Dm;
    const float* wp  = Win + (nbase + l15) * Dm + qd * 8;

#pragma unroll 2
    for (int k0 = 0; k0 < Dm; k0 += 32) {
      bf16x8 a0 = ld8_f32_bf16(a0p + k0);
      bf16x8 a1 = ld8_f32_bf16(a1p + k0);
#pragma unroll
      for (int j = 0; j < 4; ++j) {
        bf16x8 b = ld8_f32_bf16(wp + j * 16 * Dm + k0);
        acc[0][j] = MFMA(a0, b, acc[0][j]);
        acc[1][j] = MFMA(a1, b, acc[1][j]);
      }
    }
#pragma unroll
    for (int ti = 0; ti < 2; ++ti) {
#pragma unroll
      for (int j = 0; j < 4; ++j) {
        const int n = nbase + j * 16 + l15;
        const float bf = bin[n];
#pragma unroll
        for (int r = 0; r < 4; ++r) {
          const int m = mbase + ti * 16 + qd * 4 + r;
          const unsigned idx = ((unsigned)(m >> 6) * 8u + (unsigned)(n >> 6)) * 4096u +
                               (unsigned)(m & 63) * 64u + (unsigned)(n & 63);
          q_s[idx] = f32_bf16((acc[ti][j][r] + bf) * QSCALE);
        }
      }
    }
    return;
  }

  // ---------------- K+V projection ----------------
  const int idx   = blockIdx.x - 128;
  const int h     = idx >> 6;
  const int mbase = (idx & 63) * 128;

  f32x4 kacc[2][4], vacc[2][4];
#pragma unroll
  for (int ti = 0; ti < 2; ++ti)
#pragma unroll
    for (int j = 0; j < 4; ++j) { kacc[ti][j] = z4; vacc[ti][j] = z4; }

  const float* a0p = bank + (mbase + wv * 32 + l15) * Dm + qd * 8;
  const float* a1p = a0p + 16 * Dm;
  const float* wkp = Win + (Dm + h * 64 + l15) * Dm + qd * 8;
  const float* wvp = Win + (2 * Dm + h * 64 + l15) * Dm + qd * 8;

  for (int k0 = 0; k0 < Dm; k0 += 32) {
    bf16x8 a0 = ld8_f32_bf16(a0p + k0);
    bf16x8 a1 = ld8_f32_bf16(a1p + k0);
#pragma unroll
    for (int j = 0; j < 4; ++j) {
      bf16x8 wk  = ld8_f32_bf16(wkp + j * 16 * Dm + k0);
      bf16x8 wvv = ld8_f32_bf16(wvp + j * 16 * Dm + k0);
      kacc[0][j] = MFMA(a0, wk, kacc[0][j]);
      kacc[1][j] = MFMA(a1, wk, kacc[1][j]);
      vacc[0][j] = MFMA(a0, wvv, vacc[0][j]);
      vacc[1][j] = MFMA(a1, wvv, vacc[1][j]);
    }
  }

#pragma unroll
  for (int ti = 0; ti < 2; ++ti) {
#pragma unroll
    for (int j = 0; j < 4; ++j) {
      const int d = j * 16 + l15;
      const float bk = bin[Dm + h * 64 + d];
      const float bv = bin[2 * Dm + h * 64 + d];
#pragma unroll
      for (int r = 0; r < 4; ++r) {
        const int m = wv * 32 + ti * 16 + qd * 4 + r;
        Kst[m * 72 + d]  = f32_bf16(kacc[ti][j][r] + bk);
        Vst[d * 136 + m] = f32_bf16(vacc[ti][j][r] + bv);
      }
    }
  }
  __syncthreads();

#pragma unroll
  for (int p = 0; p < 4; ++p) {
    const int m = p * 32 + (threadIdx.x >> 3);
    const int d = (threadIdx.x & 7) * 8;
    *(u16x8*)(k_s + h * (Mb * 64) + (mbase + m) * 64 + d) =
        *(const u16x8*)(Kst + m * 72 + d);
  }
#pragma unroll
  for (int p = 0; p < 4; ++p) {
    const int d = p * 16 + (threadIdx.x >> 4);
    const int m = (threadIdx.x & 15) * 8;
    *(u16x8*)(vT_s + (h * 64 + d) * Mb + mbase + m) =
        *(const u16x8*)(Vst + d * 136 + m);
  }
}

// ---------------------------------------------------------------------------
// Attention partial, S^T formulation + XCD swizzle. Block decode:
//   h = blk&7 (constant per XCD under round-robin), b = (blk>>3)&31,
//   part = blk>>8. Wave wv owns key tiles m0 = part*2048 + wv*32 + it*128.
// ---------------------------------------------------------------------------
__device__ __forceinline__ void qk_tile(
    const unsigned short* __restrict__ kp, int m0, const bf16x8 bQ[4][2],
    int l15, int qd, f32x4 sfr[2][4]) {
  const f32x4 z4 = {0.f, 0.f, 0.f, 0.f};
#pragma unroll
  for (int kt = 0; kt < 2; ++kt)
#pragma unroll
    for (int sj = 0; sj < 4; ++sj) sfr[kt][sj] = z4;
#pragma unroll
  for (int kt = 0; kt < 2; ++kt) {
#pragma unroll
    for (int ks = 0; ks < 2; ++ks) {
      bf16x8 aK = *(const bf16x8*)(kp + (m0 + kt * 16 + l15) * 64 + ks * 32 + qd * 8);
#pragma unroll
      for (int sj = 0; sj < 4; ++sj) sfr[kt][sj] = MFMA(aK, bQ[sj][ks], sfr[kt][sj]);
    }
  }
}

__device__ __forceinline__ void exp_write(
    const f32x4 sfr[2][4], unsigned short* __restrict__ buf,
    int l15, int qd, float lsum[4]) {
#pragma unroll
  for (int kt = 0; kt < 2; ++kt) {
#pragma unroll
    for (int sj = 0; sj < 4; ++sj) {
      float e0 = EXP2F(sfr[kt][sj][0]);
      float e1 = EXP2F(sfr[kt][sj][1]);
      float e2 = EXP2F(sfr[kt][sj][2]);
      float e3 = EXP2F(sfr[kt][sj][3]);
      lsum[sj] += (e0 + e1) + (e2 + e3);
      uint2 dw;
      dw.x = pack_bf16_trunc(e0, e1);
      dw.y = pack_bf16_trunc(e2, e3);
      *(uint2*)(buf + (sj * 16 + l15) * PLP + kt * 16 + qd * 4) = dw;
    }
  }
}

__device__ __forceinline__ void pv_tile(
    const bf16x8 bV[4], const unsigned short* __restrict__ buf,
    int l15, int qd, f32x4 oacc[4][4]) {
  bf16x8 aP[4];
#pragma unroll
  for (int ti = 0; ti < 4; ++ti) {
    const unsigned short* pp = buf + (ti * 16 + l15) * PLP + qd * 8;
    bf16x4 lo = *(const bf16x4*)(pp);
    bf16x4 hi = *(const bf16x4*)(pp + 4);
    aP[ti] = __builtin_shufflevector(lo, hi, 0, 1, 2, 3, 4, 5, 6, 7);
  }
#pragma unroll
  for (int dt = 0; dt < 4; ++dt)
#pragma unroll
    for (int ti = 0; ti < 4; ++ti) oacc[ti][dt] = MFMA(aP[ti], bV[dt], oacc[ti][dt]);
}

__global__ __launch_bounds__(256) void attn_partial(
    const unsigned short* __restrict__ q_s,   // [bh][s][d], pre-scaled
    const unsigned short* __restrict__ k_s,   // [h][m][d]
    const unsigned short* __restrict__ vT_s,  // [h][d][m]
    unsigned short* __restrict__ O_part,      // [bh][part][s][d] bf16
    float* __restrict__ l_part) {             // [bh][part][s]
  __shared__ __align__(16) unsigned short Plds[4][2][64 * PLP];  // 36 KB
  __shared__ float lred[4][64];
  float* red = (float*)&Plds[0][0][0];  // epilogue alias

  const int lane = threadIdx.x & 63;
  const int wv   = threadIdx.x >> 6;
  const int l15  = lane & 15;
  const int qd   = lane >> 4;
  // XCD swizzle: same head on same XCD (round-robin blk%8 -> XCD)
  const int h    = blockIdx.x & 7;
  const int b    = (blockIdx.x >> 3) & 31;
  const int part = blockIdx.x >> 8;
  const int bh   = b * 8 + h;

  const unsigned short* qp = q_s + bh * 4096;
  const unsigned short* kp = k_s + h * (Mb * 64);
  const unsigned short* vp = vT_s + h * (Mb * 64);

  bf16x8 bQ[4][2];
#pragma unroll
  for (int sj = 0; sj < 4; ++sj)
#pragma unroll
    for (int ks = 0; ks < 2; ++ks)
      bQ[sj][ks] = *(const bf16x8*)(qp + (sj * 16 + l15) * 64 + ks * 32 + qd * 8);

  const f32x4 z4 = {0.f, 0.f, 0.f, 0.f};
  f32x4 oacc[4][4];
  float lsum[4] = {0.f, 0.f, 0.f, 0.f};
#pragma unroll
  for (int ti = 0; ti < 4; ++ti)
#pragma unroll
    for (int j = 0; j < 4; ++j) oacc[ti][j] = z4;

  const int mwv = part * 2048 + wv * 32;
  f32x4 sfr[2][4];

  qk_tile(kp, mwv, bQ, l15, qd, sfr);
  exp_write(sfr, Plds[wv][0], l15, qd, lsum);

  for (int it = 0; it < 15; ++it) {
    const int m0 = mwv + it * 128;
    // preload V for PV(it) BEFORE the fence so its latency overlaps QK(it+1)
    bf16x8 bVr[4];
#pragma unroll
    for (int dt = 0; dt < 4; ++dt)
      bVr[dt] = *(const bf16x8*)(vp + (dt * 16 + l15) * Mb + m0 + qd * 8);
    qk_tile(kp, m0 + 128, bQ, l15, qd, sfr);
    __asm__ volatile("s_waitcnt lgkmcnt(0)" ::: "memory");  // P(it) drained
    pv_tile(bVr, Plds[wv][it & 1], l15, qd, oacc);
    exp_write(sfr, Plds[wv][(it + 1) & 1], l15, qd, lsum);
  }
  {
    const int m0 = mwv + 15 * 128;
    bf16x8 bVr[4];
#pragma unroll
    for (int dt = 0; dt < 4; ++dt)
      bVr[dt] = *(const bf16x8*)(vp + (dt * 16 + l15) * Mb + m0 + qd * 8);
    __asm__ volatile("s_waitcnt lgkmcnt(0)" ::: "memory");
    pv_tile(bVr, Plds[wv][1], l15, qd, oacc);
  }

  // --- l: lane holds partial for s = sj*16+l15; reduce across quads/waves ---
#pragma unroll
  for (int sj = 0; sj < 4; ++sj) {
    float v = lsum[sj];
    v += __shfl_xor(v, 16);
    v += __shfl_xor(v, 32);
    if (qd == 0) lred[wv][sj * 16 + l15] = v;
  }
  __syncthreads();
  if (threadIdx.x < 64)
    l_part[(bh * 4 + part) * 64 + threadIdx.x] =
        lred[0][threadIdx.x] + lred[1][threadIdx.x] +
        lred[2][threadIdx.x] + lred[3][threadIdx.x];

  // --- O: reduce across waves in 4 chunks (red aliases Plds), store bf16 ---
  unsigned short* Ob = O_part + (bh * 4 + part) * 4096;
  for (int ti = 0; ti < 4; ++ti) {
    __syncthreads();
#pragma unroll
    for (int dt = 0; dt < 4; ++dt)
#pragma unroll
      for (int r = 0; r < 4; ++r)
        red[wv * 1024 + dt * 256 + r * 64 + lane] = oacc[ti][dt][r];
    __syncthreads();
#pragma unroll
    for (int j = 0; j < 4; ++j) {
      const int idx = j * 256 + threadIdx.x;
      const float s = red[idx] + red[1024 + idx] + red[2048 + idx] + red[3072 + idx];
      const int ln = idx & 63;
      const int r  = (idx >> 6) & 3;
      const int dt = idx >> 8;
      const int srow = ti * 16 + (ln >> 4) * 4 + r;
      const int dcol = dt * 16 + (ln & 15);
      Ob[srow * 64 + dcol] = f32_bf16(s);
    }
  }
}

// ---------------------------------------------------------------------------
// Fused: blocks [0,1024) combine attention partials -> a_stage bf16;
// blocks [1024,5120) write new_bank fp32 (overwrites the K/V scratch).
// ---------------------------------------------------------------------------
__global__ __launch_bounds__(256) void combine_bank(
    const unsigned short* __restrict__ O_part, const float* __restrict__ l_part,
    unsigned short* __restrict__ a_stage,
    const float* __restrict__ memory, const float* __restrict__ bank,
    const int* __restrict__ ptrp, float* __restrict__ out_bank) {
  if (blockIdx.x < 1024) {
    const int e  = (blockIdx.x * 256 + threadIdx.x) * 4;  // < 1048576
    const int bh = e >> 12;
    const int rem = e & 4095;
    const int s  = rem >> 6;
    const int d  = rem & 63;
    float acc[4] = {0.f, 0.f, 0.f, 0.f};
    float l = 0.f;
#pragma unroll
    for (int p = 0; p < 4; ++p) {
      u16x4 v = *(const u16x4*)(O_part + (bh * 4 + p) * 4096 + rem);
#pragma unroll
      for (int j = 0; j < 4; ++j) acc[j] += bf16_f32(v[j]);
      l += l_part[(bh * 4 + p) * 64 + s];
    }
    const int b = bh >> 3, h = bh & 7;
    u16x4 o;
#pragma unroll
    for (int j = 0; j < 4; ++j) o[j] = f32_bf16(acc[j] / l);
    *(u16x4*)(a_stage + (b * 64 + s) * 512 + h * 64 + d) = o;
  } else {
    const int t  = (blockIdx.x - 1024) * 256 + threadIdx.x;  // < 1,048,576
    const int r  = t >> 7;
    const int c4 = (t & 127) * 4;
    const int ptr = ptrp[0];
    const unsigned off = (unsigned)(r - ptr + Mb) & (Mb - 1);
    const float* src = (off < (unsigned)BSr) ? memory + off * Dm + c4
                                             : bank + r * Dm + c4;
    *(f32x4*)(out_bank + r * Dm + c4) = *(const f32x4*)src;
  }
}

// ---------------------------------------------------------------------------
// retrieved[m,n] = a_stage[m,:] @ Wout[n,:] + bout[n] -> fp32 d_out.
// Wout/bout read as fp32, packed to bf16 in-register.
// ---------------------------------------------------------------------------
__global__ __launch_bounds__(256) void out_proj(
    const unsigned short* __restrict__ A,
    const float* __restrict__ W,
    const float* __restrict__ bias,
    float* __restrict__ out) {
  const int lane = threadIdx.x & 63;
  const int wv   = threadIdx.x >> 6;
  const int l15  = lane & 15;
  const int qd   = lane >> 4;
  const int mbase = blockIdx.y * 128 + wv * 32;
  const int nbase = blockIdx.x * 64;

  const f32x4 z4 = {0.f, 0.f, 0.f, 0.f};
  f32x4 acc[2][4];
#pragma unroll
  for (int ti = 0; ti < 2; ++ti)
#pragma unroll
    for (int j = 0; j < 4; ++j) acc[ti][j] = z4;

  const unsigned short* a0p = A + (mbase + l15) * Dm + qd * 8;
  const unsigned short* a1p = a0p + 16 * Dm;
  const float* wp = W + (nbase + l15) * Dm + qd * 8;

#pragma unroll 2
  for (int k0 = 0; k0 < Dm; k0 += 32) {
    bf16x8 a0 = *(const bf16x8*)(a0p + k0);
    bf16x8 a1 = *(const bf16x8*)(a1p + k0);
#pragma unroll
    for (int j = 0; j < 4; ++j) {
      bf16x8 bfr = ld8_f32_bf16(wp + j * 16 * Dm + k0);
      acc[0][j] = MFMA(a0, bfr, acc[0][j]);
      acc[1][j] = MFMA(a1, bfr, acc[1][j]);
    }
  }

#pragma unroll
  for (int ti = 0; ti < 2; ++ti) {
#pragma unroll
    for (int j = 0; j < 4; ++j) {
      const int n = nbase + j * 16 + l15;
      const float bf = bias[n];
#pragma unroll
      for (int r = 0; r < 4; ++r) {
        const int m = mbase + ti * 16 + qd * 4 + r;
        out[m * Dm + n] = acc[ti][j][r] + bf;
      }
    }
  }
}

// ---------------------------------------------------------------------------
extern "C" void kernel_launch(void* const* d_in, const int* in_sizes, int n_in,
                              void* d_out, int out_size, void* d_ws, size_t ws_size,
                              hipStream_t stream) {
  const float* query = (const float*)d_in[0];
  const float* memry = (const float*)d_in[1];
  const float* bank  = (const float*)d_in[2];
  const float* Win   = (const float*)d_in[3];
  const float* bin   = (const float*)d_in[4];
  const float* Wout  = (const float*)d_in[5];
  const float* bout  = (const float*)d_in[6];
  const int*   ptrp  = (const int*)d_in[7];
  float* outf = (float*)d_out;

  // ws layout: 12.25 MB, no aliasing (15.8 MB proven available).
  char* ws = (char*)d_ws;
  unsigned short* q_s     = (unsigned short*)(ws);                 //  0 ..  2 MB
  unsigned short* O_part  = (unsigned short*)(ws + (2u << 20));    //  2 .. 10 MB
  float*          l_part  = (float*)(ws + (10u << 20));            // 10 .. 10.25 MB
  unsigned short* a_stage = (unsigned short*)(ws + 10747904u);     // 10.25 .. 12.25 MB

  // K/V scratch in d_out's bank region; combine_bank rewrites it afterwards.
  unsigned short* kv = (unsigned short*)(outf + 1048576);
  unsigned short* k_s  = kv;             // 8 MB: [h][m][d]
  unsigned short* vT_s = kv + 4194304;   // 8 MB: [h][d][m]

  proj_fused<<<640, 256, 0, stream>>>(query, bank, Win, bin, q_s, k_s, vT_s);

  attn_partial<<<1024, 256, 0, stream>>>(q_s, k_s, vT_s, O_part, l_part);

  combine_bank<<<5120, 256, 0, stream>>>(O_part, l_part, a_stage,
                                         memry, bank, ptrp, outf + 1048576);

  out_proj<<<dim3(8, 16), 256, 0, stream>>>(a_stage, Wout, bout, outf);
}

// Round 10
// 232.143 us; speedup vs baseline: 1.2055x; 1.2055x over previous
//
#include <hip/hip_runtime.h>

// ---------------------------------------------------------------------------
// LongTermMemoryModule, round 10. FP32 in/out. r8's bf16-canonicalized
// producers (convert_all + bf16 proj_fused: r9's fp32-direct read made
// proj latency-bound, 100 us) + r9's attention (XCD swizzle h=blk&7,
// V preload before fence, S^T b64 P-path).
// Shapes: B=32 S=64 D=512 M=8192 H=8 hd=64.
// ---------------------------------------------------------------------------

#define Dm  512
#define Mb  8192
#define BSr 2048
#define PLP 36   // P row stride (u16): 72 B rows, b64-aligned accesses

// 0.125 (1/sqrt(hd)) * log2(e): exp2 after pre-scaled QK == softmax exp
#define QSCALE 0.18033688011112042f

typedef float f32x4 __attribute__((ext_vector_type(4)));
typedef short bf16x4 __attribute__((ext_vector_type(4)));
typedef short bf16x8 __attribute__((ext_vector_type(8)));
typedef unsigned short u16x4 __attribute__((ext_vector_type(4)));
typedef unsigned short u16x8 __attribute__((ext_vector_type(8)));

#define MFMA(a, b, c) __builtin_amdgcn_mfma_f32_16x16x32_bf16((a), (b), (c), 0, 0, 0)

#if __has_builtin(__builtin_amdgcn_exp2f)
#define EXP2F(x) __builtin_amdgcn_exp2f(x)
#else
#define EXP2F(x) __expf((x)*0.6931471805599453f)
#endif

__device__ __forceinline__ unsigned short f32_bf16(float f) {
  unsigned u = __builtin_bit_cast(unsigned, f);
  u += 0x7FFFu + ((u >> 16) & 1u);   // RNE
  return (unsigned short)(u >> 16);
}
__device__ __forceinline__ float bf16_f32(unsigned short h) {
  unsigned u = ((unsigned)h) << 16;
  return __builtin_bit_cast(float, u);
}
__device__ __forceinline__ unsigned pack_bf16_trunc(float a, float b) {
  return (__builtin_bit_cast(unsigned, a) >> 16) |
         (__builtin_bit_cast(unsigned, b) & 0xFFFF0000u);
}

// ---------------------------------------------------------------------------
// Merged fp32 -> bf16 canonicalization of all 6 tensors (4 elems/thread, RNE).
// ---------------------------------------------------------------------------
__global__ __launch_bounds__(256) void convert_all(
    const float* __restrict__ q, const float* __restrict__ bank,
    const float* __restrict__ Win, const float* __restrict__ bin,
    const float* __restrict__ Wout, const float* __restrict__ bout,
    unsigned short* __restrict__ q_c, unsigned short* __restrict__ bank_c,
    unsigned short* __restrict__ Win_c, unsigned short* __restrict__ bin_c,
    unsigned short* __restrict__ Wout_c, unsigned short* __restrict__ bout_c) {
  const int e = (blockIdx.x * 256 + threadIdx.x) * 4;
  const float* src; unsigned short* dst; int off;
  if (e < 1048576)      { src = q;    dst = q_c;    off = e; }
  else if (e < 5242880) { src = bank; dst = bank_c; off = e - 1048576; }
  else if (e < 6029312) { src = Win;  dst = Win_c;  off = e - 5242880; }
  else if (e < 6030848) { src = bin;  dst = bin_c;  off = e - 6029312; }
  else if (e < 6292992) { src = Wout; dst = Wout_c; off = e - 6030848; }
  else                  { src = bout; dst = bout_c; off = e - 6292992; }
  f32x4 v = *(const f32x4*)(src + off);
  u16x4 o;
#pragma unroll
  for (int j = 0; j < 4; ++j) o[j] = f32_bf16(v[j]);
  *(u16x4*)(dst + off) = o;
}

// ---------------------------------------------------------------------------
// Fused projections (r8 form, bf16 inputs). Blocks [0,128): Q projection
// (q_s[bh][s][d], pre-scaled). Blocks [128,640): K+V (k_s[h][m][d],
// vT_s[h*64+d][m], LDS-staged coalesced stores).
// ---------------------------------------------------------------------------
__global__ __launch_bounds__(256) void proj_fused(
    const unsigned short* __restrict__ q_c,
    const unsigned short* __restrict__ bank_c,
    const unsigned short* __restrict__ Win_c,
    const unsigned short* __restrict__ bin_c,
    unsigned short* __restrict__ q_s,
    unsigned short* __restrict__ k_s,
    unsigned short* __restrict__ vT_s) {
  __shared__ __align__(16) unsigned short Kst[128 * 72];
  __shared__ __align__(16) unsigned short Vst[64 * 136];
  const int lane = threadIdx.x & 63;
  const int wv   = threadIdx.x >> 6;
  const int l15  = lane & 15;
  const int qd   = lane >> 4;
  const f32x4 z4 = {0.f, 0.f, 0.f, 0.f};

  if (blockIdx.x < 128) {
    // ---------------- Q projection ----------------
    const int mbase = (blockIdx.x >> 3) * 128 + wv * 32;
    const int nbase = (blockIdx.x & 7) * 64;
    f32x4 acc[2][4];
#pragma unroll
    for (int ti = 0; ti < 2; ++ti)
#pragma unroll
      for (int j = 0; j < 4; ++j) acc[ti][j] = z4;

    const unsigned short* a0p = q_c + (mbase + l15) * Dm + qd * 8;
    const unsigned short* a1p = a0p + 16 * Dm;
    const unsigned short* wp  = Win_c + (nbase + l15) * Dm + qd * 8;

#pragma unroll 4
    for (int k0 = 0; k0 < Dm; k0 += 32) {
      bf16x8 a0 = *(const bf16x8*)(a0p + k0);
      bf16x8 a1 = *(const bf16x8*)(a1p + k0);
#pragma unroll
      for (int j = 0; j < 4; ++j) {
        bf16x8 b = *(const bf16x8*)(wp + j * 16 * Dm + k0);
        acc[0][j] = MFMA(a0, b, acc[0][j]);
        acc[1][j] = MFMA(a1, b, acc[1][j]);
      }
    }
#pragma unroll
    for (int ti = 0; ti < 2; ++ti) {
#pragma unroll
      for (int j = 0; j < 4; ++j) {
        const int n = nbase + j * 16 + l15;
        const float bf = bf16_f32(bin_c[n]);
#pragma unroll
        for (int r = 0; r < 4; ++r) {
          const int m = mbase + ti * 16 + qd * 4 + r;
          const unsigned idx = ((unsigned)(m >> 6) * 8u + (unsigned)(n >> 6)) * 4096u +
                               (unsigned)(m & 63) * 64u + (unsigned)(n & 63);
          q_s[idx] = f32_bf16((acc[ti][j][r] + bf) * QSCALE);
        }
      }
    }
    return;
  }

  // ---------------- K+V projection ----------------
  const int idx   = blockIdx.x - 128;
  const int h     = idx >> 6;
  const int mbase = (idx & 63) * 128;

  f32x4 kacc[2][4], vacc[2][4];
#pragma unroll
  for (int ti = 0; ti < 2; ++ti)
#pragma unroll
    for (int j = 0; j < 4; ++j) { kacc[ti][j] = z4; vacc[ti][j] = z4; }

  const unsigned short* a0p = bank_c + (mbase + wv * 32 + l15) * Dm + qd * 8;
  const unsigned short* a1p = a0p + 16 * Dm;
  const unsigned short* wkp = Win_c + (Dm + h * 64 + l15) * Dm + qd * 8;
  const unsigned short* wvp = Win_c + (2 * Dm + h * 64 + l15) * Dm + qd * 8;

#pragma unroll 2
  for (int k0 = 0; k0 < Dm; k0 += 32) {
    bf16x8 a0 = *(const bf16x8*)(a0p + k0);
    bf16x8 a1 = *(const bf16x8*)(a1p + k0);
#pragma unroll
    for (int j = 0; j < 4; ++j) {
      bf16x8 wk  = *(const bf16x8*)(wkp + j * 16 * Dm + k0);
      bf16x8 wvv = *(const bf16x8*)(wvp + j * 16 * Dm + k0);
      kacc[0][j] = MFMA(a0, wk, kacc[0][j]);
      kacc[1][j] = MFMA(a1, wk, kacc[1][j]);
      vacc[0][j] = MFMA(a0, wvv, vacc[0][j]);
      vacc[1][j] = MFMA(a1, wvv, vacc[1][j]);
    }
  }

#pragma unroll
  for (int ti = 0; ti < 2; ++ti) {
#pragma unroll
    for (int j = 0; j < 4; ++j) {
      const int d = j * 16 + l15;
      const float bk = bf16_f32(bin_c[Dm + h * 64 + d]);
      const float bv = bf16_f32(bin_c[2 * Dm + h * 64 + d]);
#pragma unroll
      for (int r = 0; r < 4; ++r) {
        const int m = wv * 32 + ti * 16 + qd * 4 + r;
        Kst[m * 72 + d]  = f32_bf16(kacc[ti][j][r] + bk);
        Vst[d * 136 + m] = f32_bf16(vacc[ti][j][r] + bv);
      }
    }
  }
  __syncthreads();

#pragma unroll
  for (int p = 0; p < 4; ++p) {
    const int m = p * 32 + (threadIdx.x >> 3);
    const int d = (threadIdx.x & 7) * 8;
    *(u16x8*)(k_s + h * (Mb * 64) + (mbase + m) * 64 + d) =
        *(const u16x8*)(Kst + m * 72 + d);
  }
#pragma unroll
  for (int p = 0; p < 4; ++p) {
    const int d = p * 16 + (threadIdx.x >> 4);
    const int m = (threadIdx.x & 15) * 8;
    *(u16x8*)(vT_s + (h * 64 + d) * Mb + mbase + m) =
        *(const u16x8*)(Vst + d * 136 + m);
  }
}

// ---------------------------------------------------------------------------
// Attention partial, S^T formulation + XCD swizzle (h = blk&7: one head per
// XCD under round-robin -> K/V working set ~4 MB fits per-XCD L2).
// ---------------------------------------------------------------------------
__device__ __forceinline__ void qk_tile(
    const unsigned short* __restrict__ kp, int m0, const bf16x8 bQ[4][2],
    int l15, int qd, f32x4 sfr[2][4]) {
  const f32x4 z4 = {0.f, 0.f, 0.f, 0.f};
#pragma unroll
  for (int kt = 0; kt < 2; ++kt)
#pragma unroll
    for (int sj = 0; sj < 4; ++sj) sfr[kt][sj] = z4;
#pragma unroll
  for (int kt = 0; kt < 2; ++kt) {
#pragma unroll
    for (int ks = 0; ks < 2; ++ks) {
      bf16x8 aK = *(const bf16x8*)(kp + (m0 + kt * 16 + l15) * 64 + ks * 32 + qd * 8);
#pragma unroll
      for (int sj = 0; sj < 4; ++sj) sfr[kt][sj] = MFMA(aK, bQ[sj][ks], sfr[kt][sj]);
    }
  }
}

__device__ __forceinline__ void exp_write(
    const f32x4 sfr[2][4], unsigned short* __restrict__ buf,
    int l15, int qd, float lsum[4]) {
#pragma unroll
  for (int kt = 0; kt < 2; ++kt) {
#pragma unroll
    for (int sj = 0; sj < 4; ++sj) {
      float e0 = EXP2F(sfr[kt][sj][0]);
      float e1 = EXP2F(sfr[kt][sj][1]);
      float e2 = EXP2F(sfr[kt][sj][2]);
      float e3 = EXP2F(sfr[kt][sj][3]);
      lsum[sj] += (e0 + e1) + (e2 + e3);
      uint2 dw;
      dw.x = pack_bf16_trunc(e0, e1);
      dw.y = pack_bf16_trunc(e2, e3);
      *(uint2*)(buf + (sj * 16 + l15) * PLP + kt * 16 + qd * 4) = dw;
    }
  }
}

__device__ __forceinline__ void pv_tile(
    const bf16x8 bV[4], const unsigned short* __restrict__ buf,
    int l15, int qd, f32x4 oacc[4][4]) {
  bf16x8 aP[4];
#pragma unroll
  for (int ti = 0; ti < 4; ++ti) {
    const unsigned short* pp = buf + (ti * 16 + l15) * PLP + qd * 8;
    bf16x4 lo = *(const bf16x4*)(pp);
    bf16x4 hi = *(const bf16x4*)(pp + 4);
    aP[ti] = __builtin_shufflevector(lo, hi, 0, 1, 2, 3, 4, 5, 6, 7);
  }
#pragma unroll
  for (int dt = 0; dt < 4; ++dt)
#pragma unroll
    for (int ti = 0; ti < 4; ++ti) oacc[ti][dt] = MFMA(aP[ti], bV[dt], oacc[ti][dt]);
}

__global__ __launch_bounds__(256) void attn_partial(
    const unsigned short* __restrict__ q_s,   // [bh][s][d], pre-scaled
    const unsigned short* __restrict__ k_s,   // [h][m][d]
    const unsigned short* __restrict__ vT_s,  // [h][d][m]
    unsigned short* __restrict__ O_part,      // [bh][part][s][d] bf16
    float* __restrict__ l_part) {             // [bh][part][s]
  __shared__ __align__(16) unsigned short Plds[4][2][64 * PLP];  // 36 KB
  __shared__ float lred[4][64];
  float* red = (float*)&Plds[0][0][0];  // epilogue alias

  const int lane = threadIdx.x & 63;
  const int wv   = threadIdx.x >> 6;
  const int l15  = lane & 15;
  const int qd   = lane >> 4;
  // XCD swizzle: same head on same XCD (round-robin blk%8 -> XCD)
  const int h    = blockIdx.x & 7;
  const int b    = (blockIdx.x >> 3) & 31;
  const int part = blockIdx.x >> 8;
  const int bh   = b * 8 + h;

  const unsigned short* qp = q_s + bh * 4096;
  const unsigned short* kp = k_s + h * (Mb * 64);
  const unsigned short* vp = vT_s + h * (Mb * 64);

  bf16x8 bQ[4][2];
#pragma unroll
  for (int sj = 0; sj < 4; ++sj)
#pragma unroll
    for (int ks = 0; ks < 2; ++ks)
      bQ[sj][ks] = *(const bf16x8*)(qp + (sj * 16 + l15) * 64 + ks * 32 + qd * 8);

  const f32x4 z4 = {0.f, 0.f, 0.f, 0.f};
  f32x4 oacc[4][4];
  float lsum[4] = {0.f, 0.f, 0.f, 0.f};
#pragma unroll
  for (int ti = 0; ti < 4; ++ti)
#pragma unroll
    for (int j = 0; j < 4; ++j) oacc[ti][j] = z4;

  const int mwv = part * 2048 + wv * 32;
  f32x4 sfr[2][4];

  qk_tile(kp, mwv, bQ, l15, qd, sfr);
  exp_write(sfr, Plds[wv][0], l15, qd, lsum);

  for (int it = 0; it < 15; ++it) {
    const int m0 = mwv + it * 128;
    // preload V for PV(it) BEFORE the fence so its latency overlaps QK(it+1)
    bf16x8 bVr[4];
#pragma unroll
    for (int dt = 0; dt < 4; ++dt)
      bVr[dt] = *(const bf16x8*)(vp + (dt * 16 + l15) * Mb + m0 + qd * 8);
    qk_tile(kp, m0 + 128, bQ, l15, qd, sfr);
    __asm__ volatile("s_waitcnt lgkmcnt(0)" ::: "memory");  // P(it) drained
    pv_tile(bVr, Plds[wv][it & 1], l15, qd, oacc);
    exp_write(sfr, Plds[wv][(it + 1) & 1], l15, qd, lsum);
  }
  {
    const int m0 = mwv + 15 * 128;
    bf16x8 bVr[4];
#pragma unroll
    for (int dt = 0; dt < 4; ++dt)
      bVr[dt] = *(const bf16x8*)(vp + (dt * 16 + l15) * Mb + m0 + qd * 8);
    __asm__ volatile("s_waitcnt lgkmcnt(0)" ::: "memory");
    pv_tile(bVr, Plds[wv][1], l15, qd, oacc);
  }

  // --- l: lane holds partial for s = sj*16+l15; reduce across quads/waves ---
#pragma unroll
  for (int sj = 0; sj < 4; ++sj) {
    float v = lsum[sj];
    v += __shfl_xor(v, 16);
    v += __shfl_xor(v, 32);
    if (qd == 0) lred[wv][sj * 16 + l15] = v;
  }
  __syncthreads();
  if (threadIdx.x < 64)
    l_part[(bh * 4 + part) * 64 + threadIdx.x] =
        lred[0][threadIdx.x] + lred[1][threadIdx.x] +
        lred[2][threadIdx.x] + lred[3][threadIdx.x];

  // --- O: reduce across waves in 4 chunks (red aliases Plds), store bf16 ---
  unsigned short* Ob = O_part + (bh * 4 + part) * 4096;
  for (int ti = 0; ti < 4; ++ti) {
    __syncthreads();
#pragma unroll
    for (int dt = 0; dt < 4; ++dt)
#pragma unroll
      for (int r = 0; r < 4; ++r)
        red[wv * 1024 + dt * 256 + r * 64 + lane] = oacc[ti][dt][r];
    __syncthreads();
#pragma unroll
    for (int j = 0; j < 4; ++j) {
      const int idx = j * 256 + threadIdx.x;
      const float s = red[idx] + red[1024 + idx] + red[2048 + idx] + red[3072 + idx];
      const int ln = idx & 63;
      const int r  = (idx >> 6) & 3;
      const int dt = idx >> 8;
      const int srow = ti * 16 + (ln >> 4) * 4 + r;
      const int dcol = dt * 16 + (ln & 15);
      Ob[srow * 64 + dcol] = f32_bf16(s);
    }
  }
}

// ---------------------------------------------------------------------------
// Fused: blocks [0,1024) combine attention partials -> a_stage bf16;
// blocks [1024,5120) write new_bank fp32 (overwrites the K/V scratch).
// ---------------------------------------------------------------------------
__global__ __launch_bounds__(256) void combine_bank(
    const unsigned short* __restrict__ O_part, const float* __restrict__ l_part,
    unsigned short* __restrict__ a_stage,
    const float* __restrict__ memory, const float* __restrict__ bank,
    const int* __restrict__ ptrp, float* __restrict__ out_bank) {
  if (blockIdx.x < 1024) {
    const int e  = (blockIdx.x * 256 + threadIdx.x) * 4;  // < 1048576
    const int bh = e >> 12;
    const int rem = e & 4095;
    const int s  = rem >> 6;
    const int d  = rem & 63;
    float acc[4] = {0.f, 0.f, 0.f, 0.f};
    float l = 0.f;
#pragma unroll
    for (int p = 0; p < 4; ++p) {
      u16x4 v = *(const u16x4*)(O_part + (bh * 4 + p) * 4096 + rem);
#pragma unroll
      for (int j = 0; j < 4; ++j) acc[j] += bf16_f32(v[j]);
      l += l_part[(bh * 4 + p) * 64 + s];
    }
    const int b = bh >> 3, h = bh & 7;
    u16x4 o;
#pragma unroll
    for (int j = 0; j < 4; ++j) o[j] = f32_bf16(acc[j] / l);
    *(u16x4*)(a_stage + (b * 64 + s) * 512 + h * 64 + d) = o;
  } else {
    const int t  = (blockIdx.x - 1024) * 256 + threadIdx.x;  // < 1,048,576
    const int r  = t >> 7;
    const int c4 = (t & 127) * 4;
    const int ptr = ptrp[0];
    const unsigned off = (unsigned)(r - ptr + Mb) & (Mb - 1);
    const float* src = (off < (unsigned)BSr) ? memory + off * Dm + c4
                                             : bank + r * Dm + c4;
    *(f32x4*)(out_bank + r * Dm + c4) = *(const f32x4*)src;
  }
}

// ---------------------------------------------------------------------------
// retrieved[m,n] = a_stage[m,:] @ Wout[n,:] + bout[n] -> fp32 d_out.
// ---------------------------------------------------------------------------
__global__ __launch_bounds__(256) void out_proj(
    const unsigned short* __restrict__ A,
    const unsigned short* __restrict__ W,
    const unsigned short* __restrict__ bias,
    float* __restrict__ out) {
  const int lane = threadIdx.x & 63;
  const int wv   = threadIdx.x >> 6;
  const int l15  = lane & 15;
  const int qd   = lane >> 4;
  const int mbase = blockIdx.y * 128 + wv * 32;
  const int nbase = blockIdx.x * 64;

  const f32x4 z4 = {0.f, 0.f, 0.f, 0.f};
  f32x4 acc[2][4];
#pragma unroll
  for (int ti = 0; ti < 2; ++ti)
#pragma unroll
    for (int j = 0; j < 4; ++j) acc[ti][j] = z4;

  const unsigned short* a0p = A + (mbase + l15) * Dm + qd * 8;
  const unsigned short* a1p = a0p + 16 * Dm;
  const unsigned short* wp  = W + (nbase + l15) * Dm + qd * 8;

#pragma unroll 4
  for (int k0 = 0; k0 < Dm; k0 += 32) {
    bf16x8 a0 = *(const bf16x8*)(a0p + k0);
    bf16x8 a1 = *(const bf16x8*)(a1p + k0);
#pragma unroll
    for (int j = 0; j < 4; ++j) {
      bf16x8 bfr = *(const bf16x8*)(wp + j * 16 * Dm + k0);
      acc[0][j] = MFMA(a0, bfr, acc[0][j]);
      acc[1][j] = MFMA(a1, bfr, acc[1][j]);
    }
  }

#pragma unroll
  for (int ti = 0; ti < 2; ++ti) {
#pragma unroll
    for (int j = 0; j < 4; ++j) {
      const int n = nbase + j * 16 + l15;
      const float bf = bf16_f32(bias[n]);
#pragma unroll
      for (int r = 0; r < 4; ++r) {
        const int m = mbase + ti * 16 + qd * 4 + r;
        out[m * Dm + n] = acc[ti][j][r] + bf;
      }
    }
  }
}

// ---------------------------------------------------------------------------
extern "C" void kernel_launch(void* const* d_in, const int* in_sizes, int n_in,
                              void* d_out, int out_size, void* d_ws, size_t ws_size,
                              hipStream_t stream) {
  const float* query = (const float*)d_in[0];
  const float* memry = (const float*)d_in[1];
  const float* bank  = (const float*)d_in[2];
  const float* Win   = (const float*)d_in[3];
  const float* bin   = (const float*)d_in[4];
  const float* Wout  = (const float*)d_in[5];
  const float* bout  = (const float*)d_in[6];
  const int*   ptrp  = (const int*)d_in[7];
  float* outf = (float*)d_out;

  // ws layout (14.3 MB, r8-proven). Lifetime-disjoint aliases:
  // a_stage reuses q_c; O_part reuses bank_c.
  char* ws = (char*)d_ws;
  unsigned short* q_c     = (unsigned short*)(ws);                 //  0 ..  2 MB
  unsigned short* a_stage = (unsigned short*)(ws);                 //  (alias)
  unsigned short* bank_c  = (unsigned short*)(ws + (2u << 20));    //  2 .. 10 MB
  unsigned short* O_part  = (unsigned short*)(ws + (2u << 20));    //  (alias)
  unsigned short* Win_c   = (unsigned short*)(ws + (10u << 20));   // 10 .. 11.5 MB
  unsigned short* Wout_c  = (unsigned short*)(ws + 12058624u);     // 11.5 .. 12 MB
  unsigned short* q_s     = (unsigned short*)(ws + (12u << 20));   // 12 .. 14 MB
  float*          l_part  = (float*)(ws + (14u << 20));            // 14 .. 14.25 MB
  unsigned short* bin_c   = (unsigned short*)(ws + 14942208u);
  unsigned short* bout_c  = (unsigned short*)(ws + 14945280u);

  // K/V scratch in d_out's bank region; combine_bank rewrites it afterwards.
  unsigned short* kv = (unsigned short*)(outf + 1048576);
  unsigned short* k_s  = kv;             // 8 MB: [h][m][d]
  unsigned short* vT_s = kv + 4194304;   // 8 MB: [h][d][m]

  convert_all<<<6146, 256, 0, stream>>>(query, bank, Win, bin, Wout, bout,
                                        q_c, bank_c, Win_c, bin_c, Wout_c, bout_c);

  proj_fused<<<640, 256, 0, stream>>>(q_c, bank_c, Win_c, bin_c, q_s, k_s, vT_s);

  attn_partial<<<1024, 256, 0, stream>>>(q_s, k_s, vT_s, O_part, l_part);

  combine_bank<<<5120, 256, 0, stream>>>(O_part, l_part, a_stage,
                                         memry, bank, ptrp, outf + 1048576);

  out_proj<<<dim3(8, 16), 256, 0, stream>>>(a_stage, Wout_c, bout_c, outf);
}